// Round 8
// baseline (238.545 us; speedup 1.0000x reference)
//
#include <hip/hip_runtime.h>

#define BDIM 256

constexpr int K      = 32;
constexpr int L1     = 1024;
constexpr int L2C    = 15;
constexpr int L3C    = 32;
constexpr int COUNT  = 9;
constexpr int NF     = 22528;
constexpr int W1COLS = COUNT * (L2C + 1); // 144
constexpr int W2COLS = COUNT * L3C;       // 288

__device__ __forceinline__ float clip01(float x) {
    return fminf(fmaxf(x, 0.0f), 1.0f);
}

// ---- fp32 -> uint8 (excess-128) per-row quantization of W_ft ----
// Lane owns 16 consecutive cols -> one uint4 (16 B) store per lane.
// Rebuilt every iteration (workspace re-poisoned; R1 proved memoization
// never survives).
__global__ __launch_bounds__(256) void quant_w_ft(const float* __restrict__ src,
                                                  unsigned char* __restrict__ dst,
                                                  float* __restrict__ scales,
                                                  int nrows) {
    const int wq   = threadIdx.x >> 6;          // wave in block
    const int lane = threadIdx.x & 63;
    const int row  = blockIdx.x * 4 + wq;
    if (row >= nrows) return;

    const float* s = src + (long)row * L1 + lane * 16;
    float4 v[4];
    v[0] = *(const float4*)(s);
    v[1] = *(const float4*)(s + 4);
    v[2] = *(const float4*)(s + 8);
    v[3] = *(const float4*)(s + 12);

    float m = 0.0f;
    #pragma unroll
    for (int i = 0; i < 4; ++i)
        m = fmaxf(m, fmaxf(fmaxf(fabsf(v[i].x), fabsf(v[i].y)),
                           fmaxf(fabsf(v[i].z), fabsf(v[i].w))));
    #pragma unroll
    for (int off = 32; off >= 1; off >>= 1)
        m = fmaxf(m, __shfl_xor(m, off));

    const float mm    = fmaxf(m, 1e-30f);
    const float scale = mm / 127.0f;
    const float inv   = 127.0f / mm;

    uint4 pk;
    unsigned* pw = (unsigned*)&pk;
    #pragma unroll
    for (int i = 0; i < 4; ++i) {
        int q0 = (int)rintf(v[i].x * inv) + 128;
        int q1 = (int)rintf(v[i].y * inv) + 128;
        int q2 = (int)rintf(v[i].z * inv) + 128;
        int q3 = (int)rintf(v[i].w * inv) + 128;
        q0 = max(0, min(255, q0)); q1 = max(0, min(255, q1));
        q2 = max(0, min(255, q2)); q3 = max(0, min(255, q3));
        pw[i] = (unsigned)q0 | ((unsigned)q1 << 8) |
                ((unsigned)q2 << 16) | ((unsigned)q3 << 24);
    }
    *(uint4*)(dst + (long)row * L1 + lane * 16) = pk;
    if (lane == 0) scales[row] = scale;
}

// ---- fused NNUE forward, uint8 table, 2 batch rows per block ----
// R8: gather is latency-bound (process of elimination R3..R7: not HBM,
// not bytes, not instr issue, not conflicts, not unpack). Double the
// per-wave MLP: each thread gathers for TWO batch rows (independent load
// streams interleaved in the k-loop), grid halves to Bn/2. Tail = R4's
// exact verified structure, run sequentially per row (tail proven ~free:
// R2/R3 arithmetic gave tail ~= 0).
__global__ __launch_bounds__(BDIM) void nnue_fused_q2(
    const float* __restrict__ us,
    const float* __restrict__ them,
    const int*   __restrict__ wi,
    const float* __restrict__ wv,
    const int*   __restrict__ bi,
    const float* __restrict__ bvv,
    const int*   __restrict__ lsi,
    const unsigned char* __restrict__ Wq,
    const float* __restrict__ scl,
    const float* __restrict__ b_ft,
    const float* __restrict__ W1,
    const float* __restrict__ b1,
    const float* __restrict__ W2,
    const float* __restrict__ b2,
    const float* __restrict__ W3,
    const float* __restrict__ b3,
    float* __restrict__ out,
    int Bn)
{
    const int t  = threadIdx.x;
    const int r0 = blockIdx.x * 2;          // first batch row of this block
    const int r1 = min(r0 + 1, Bn - 1);     // second (dup-safe for odd Bn)

    __shared__ int   s_idx[2][2][K];        // [row][persp][k]
    __shared__ float s_val[2][2][K];        // val * scale[row]
    __shared__ float s_wp[2][L1];           // [row]: white accumulator
    __shared__ float s_bp[2][L1];           // [row]: black accumulator
    __shared__ float s_red[4 * 16];
    __shared__ float s_v[2 * L2C];
    __shared__ float s_p2[L3C];
    __shared__ float s_l1f;

    // ---- stage sparse indices/values for both rows (128 threads) ----
    if (t < 128) {
        const int g     = t >> 5;           // 0..3
        const int kk    = t & 31;
        const int row   = g >> 1;           // 0,1
        const int persp = g & 1;            // 0=white, 1=black
        const int brow  = row == 0 ? r0 : r1;
        int ii; float vv;
        if (persp == 0) { ii = wi[brow * K + kk]; vv = wv[brow * K + kk]; }
        else            { ii = bi[brow * K + kk]; vv = bvv[brow * K + kk]; }
        s_idx[row][persp][kk] = ii;
        s_val[row][persp][kk] = vv * scl[ii];
    }
    __syncthreads();

    // ---- feature transform: 2 independent 8 B load streams per thread ----
    const int   half = t >> 7;        // 0 = white, 1 = black
    const int   tc   = t & 127;
    const int   c8   = tc * 8;        // byte offset == col offset (1 B/col)
    const int*   i0 = s_idx[0][half];
    const int*   i1 = s_idx[1][half];
    const float* v0 = s_val[0][half];
    const float* v1 = s_val[1][half];

    float acc0[8], acc1[8];
    {
        const float4 bf0 = *(const float4*)(b_ft + c8);
        const float4 bf1 = *(const float4*)(b_ft + c8 + 4);
        acc0[0] = bf0.x; acc0[1] = bf0.y; acc0[2] = bf0.z; acc0[3] = bf0.w;
        acc0[4] = bf1.x; acc0[5] = bf1.y; acc0[6] = bf1.z; acc0[7] = bf1.w;
        #pragma unroll
        for (int j = 0; j < 8; ++j) acc1[j] = acc0[j];
    }

    float sum0 = 0.0f, sum1 = 0.0f;
    #pragma unroll 8
    for (int k = 0; k < K; ++k) {
        const float vs0 = v0[k];
        const float vs1 = v1[k];
        const uint2 qa  = *(const uint2*)(Wq + ((long)i0[k] << 10) + c8);
        const uint2 qb  = *(const uint2*)(Wq + ((long)i1[k] << 10) + c8);
        sum0 += vs0; sum1 += vs1;
        acc0[0] = fmaf(vs0, (float)( qa.x        & 0xffu), acc0[0]);
        acc0[1] = fmaf(vs0, (float)((qa.x >>  8) & 0xffu), acc0[1]);
        acc0[2] = fmaf(vs0, (float)((qa.x >> 16) & 0xffu), acc0[2]);
        acc0[3] = fmaf(vs0, (float)( qa.x >> 24        ), acc0[3]);
        acc0[4] = fmaf(vs0, (float)( qa.y        & 0xffu), acc0[4]);
        acc0[5] = fmaf(vs0, (float)((qa.y >>  8) & 0xffu), acc0[5]);
        acc0[6] = fmaf(vs0, (float)((qa.y >> 16) & 0xffu), acc0[6]);
        acc0[7] = fmaf(vs0, (float)( qa.y >> 24        ), acc0[7]);
        acc1[0] = fmaf(vs1, (float)( qb.x        & 0xffu), acc1[0]);
        acc1[1] = fmaf(vs1, (float)((qb.x >>  8) & 0xffu), acc1[1]);
        acc1[2] = fmaf(vs1, (float)((qb.x >> 16) & 0xffu), acc1[2]);
        acc1[3] = fmaf(vs1, (float)( qb.x >> 24        ), acc1[3]);
        acc1[4] = fmaf(vs1, (float)( qb.y        & 0xffu), acc1[4]);
        acc1[5] = fmaf(vs1, (float)((qb.y >>  8) & 0xffu), acc1[5]);
        acc1[6] = fmaf(vs1, (float)((qb.y >> 16) & 0xffu), acc1[6]);
        acc1[7] = fmaf(vs1, (float)( qb.y >> 24        ), acc1[7]);
    }
    #pragma unroll
    for (int j = 0; j < 8; ++j) {
        acc0[j] = fmaf(sum0, -128.0f, acc0[j]);
        acc1[j] = fmaf(sum1, -128.0f, acc1[j]);
    }

    {
        float* d0 = (half == 0 ? s_wp[0] : s_bp[0]) + c8;
        float* d1 = (half == 0 ? s_wp[1] : s_bp[1]) + c8;
        #pragma unroll
        for (int j = 0; j < 8; ++j) { d0[j] = acc0[j]; d1[j] = acc1[j]; }
    }
    __syncthreads();

    const float cc   = 127.0f / 128.0f;
    const int   lane = t & 63;
    const int   wid  = t >> 6;

    // ---- tail: R4's exact verified structure, once per row ----
    for (int r = 0; r < 2; ++r) {
        const int   brow = r == 0 ? r0 : r1;
        const float u    = us[brow];
        const float th   = them[brow];
        const int   idx  = lsi[brow];
        const float* swp = s_wp[r];
        const float* sbp = s_bp[r];

        float p[16];
        #pragma unroll
        for (int j = 0; j < 16; ++j) p[j] = 0.0f;

        const float* W1sel = W1 + idx * (L2C + 1);
        const int e0 = t * 4;
        #pragma unroll
        for (int q = 0; q < 4; ++q) {
            const int e = e0 + q;
            float l0p;
            if (e < 512) {
                const float a0 = clip01(u * swp[e]       + th * sbp[e]);
                const float a1 = clip01(u * swp[e + 512] + th * sbp[e + 512]);
                l0p = a0 * a1;
            } else {
                const int   c   = e - 512;
                const float b0  = clip01(u * sbp[c] + th * swp[c]);
                const float b1v = clip01(u * sbp[e] + th * swp[e]);
                l0p = b0 * b1v;
            }
            l0p *= cc;
            const float* wrow = W1sel + e * W1COLS;
            #pragma unroll
            for (int j = 0; j < 16; ++j) p[j] = fmaf(l0p, wrow[j], p[j]);
        }

        #pragma unroll
        for (int j = 0; j < 16; ++j) {
            float v = p[j];
            v += __shfl_down(v, 32);
            v += __shfl_down(v, 16);
            v += __shfl_down(v, 8);
            v += __shfl_down(v, 4);
            v += __shfl_down(v, 2);
            v += __shfl_down(v, 1);
            if (lane == 0) s_red[wid * 16 + j] = v;
        }
        __syncthreads();

        if (t < 16) {
            float x1 = s_red[t] + s_red[16 + t] + s_red[32 + t] + s_red[48 + t]
                     + b1[idx * (L2C + 1) + t];
            if (t == 15) {
                s_l1f = x1;
            } else {
                float cx = clip01(x1);
                s_v[t]       = cx * cx * cc;
                s_v[L2C + t] = cx * cc;
            }
        }
        __syncthreads();

        if (t < L3C) {
            float acc2 = b2[idx * L3C + t];
            #pragma unroll
            for (int rr = 0; rr < 2 * L2C; ++rr)
                acc2 = fmaf(s_v[rr], W2[rr * W2COLS + idx * L3C + t], acc2);
            s_p2[t] = clip01(acc2) * W3[t * COUNT + idx];
        }
        __syncthreads();

        if (t == 0 && (r == 0 || r1 != r0)) {
            float s = 0.0f;
            #pragma unroll
            for (int m = 0; m < L3C; ++m) s += s_p2[m];
            out[brow] = s + b3[idx] + s_l1f;
        }
        if (r == 0) __syncthreads();   // protect s_red/s_v/s_p2 reuse
    }
}

// ---- fp32 single-kernel fallback (ws too small) — verified 186 us ----
__global__ __launch_bounds__(BDIM) void nnue_fused_f(
    const float* __restrict__ us,
    const float* __restrict__ them,
    const int*   __restrict__ wi,
    const float* __restrict__ wv,
    const int*   __restrict__ bi,
    const float* __restrict__ bvv,
    const int*   __restrict__ lsi,
    const float* __restrict__ W_ft,
    const float* __restrict__ b_ft,
    const float* __restrict__ W1,
    const float* __restrict__ b1,
    const float* __restrict__ W2,
    const float* __restrict__ b2,
    const float* __restrict__ W3,
    const float* __restrict__ b3,
    float* __restrict__ out)
{
    const int b = blockIdx.x;
    const int t = threadIdx.x;

    __shared__ int   s_idx[2 * K];
    __shared__ float s_val[2 * K];
    __shared__ float s_l0[2 * L1];
    __shared__ float s_red[4 * 16];
    __shared__ float s_v[2 * L2C];
    __shared__ float s_p2[L3C];
    __shared__ float s_l1f;

    if (t < K)          { s_idx[t] = wi[b * K + t];        s_val[t] = wv[b * K + t]; }
    else if (t < 2 * K) { s_idx[t] = bi[b * K + (t - K)];  s_val[t] = bvv[b * K + (t - K)]; }
    __syncthreads();

    const int c4 = t * 4;
    float4 accW = *(const float4*)(b_ft + c4);
    float4 accB = accW;

    #pragma unroll 8
    for (int k = 0; k < K; ++k) {
        const float  vwk = s_val[k];
        const float  vbk = s_val[K + k];
        const float4 rw  = *(const float4*)(W_ft + ((long)s_idx[k]     << 10) + c4);
        const float4 rb  = *(const float4*)(W_ft + ((long)s_idx[K + k] << 10) + c4);
        accW.x = fmaf(vwk, rw.x, accW.x);
        accW.y = fmaf(vwk, rw.y, accW.y);
        accW.z = fmaf(vwk, rw.z, accW.z);
        accW.w = fmaf(vwk, rw.w, accW.w);
        accB.x = fmaf(vbk, rb.x, accB.x);
        accB.y = fmaf(vbk, rb.y, accB.y);
        accB.z = fmaf(vbk, rb.z, accB.z);
        accB.w = fmaf(vbk, rb.w, accB.w);
    }

    const float u  = us[b];
    const float th = them[b];
    float4 A, Bv;
    A.x  = clip01(u * accW.x + th * accB.x);
    A.y  = clip01(u * accW.y + th * accB.y);
    A.z  = clip01(u * accW.z + th * accB.z);
    A.w  = clip01(u * accW.w + th * accB.w);
    Bv.x = clip01(u * accB.x + th * accW.x);
    Bv.y = clip01(u * accB.y + th * accW.y);
    Bv.z = clip01(u * accB.z + th * accW.z);
    Bv.w = clip01(u * accB.w + th * accW.w);
    *(float4*)(s_l0 + c4)      = A;
    *(float4*)(s_l0 + L1 + c4) = Bv;
    __syncthreads();

    const int   idx = lsi[b];
    const float cc  = 127.0f / 128.0f;

    float p[16];
    #pragma unroll
    for (int j = 0; j < 16; ++j) p[j] = 0.0f;

    const float* W1sel = W1 + idx * (L2C + 1);
    #pragma unroll
    for (int q = 0; q < 4; ++q) {
        const int e = c4 + q;
        float l0p;
        if (e < 512) l0p = s_l0[e] * s_l0[e + 512];
        else         l0p = s_l0[e + 512] * s_l0[e + 1024];
        l0p *= cc;
        const float* wrow = W1sel + e * W1COLS;
        #pragma unroll
        for (int j = 0; j < 16; ++j) p[j] = fmaf(l0p, wrow[j], p[j]);
    }

    const int lane = t & 63;
    const int wid  = t >> 6;
    #pragma unroll
    for (int j = 0; j < 16; ++j) {
        float v = p[j];
        v += __shfl_down(v, 32);
        v += __shfl_down(v, 16);
        v += __shfl_down(v, 8);
        v += __shfl_down(v, 4);
        v += __shfl_down(v, 2);
        v += __shfl_down(v, 1);
        if (lane == 0) s_red[wid * 16 + j] = v;
    }
    __syncthreads();

    if (t < 16) {
        float x1 = s_red[t] + s_red[16 + t] + s_red[32 + t] + s_red[48 + t]
                 + b1[idx * (L2C + 1) + t];
        if (t == 15) {
            s_l1f = x1;
        } else {
            float cx = clip01(x1);
            s_v[t]       = cx * cx * cc;
            s_v[L2C + t] = cx * cc;
        }
    }
    __syncthreads();

    if (t < L3C) {
        float acc = b2[idx * L3C + t];
        #pragma unroll
        for (int r = 0; r < 2 * L2C; ++r)
            acc = fmaf(s_v[r], W2[r * W2COLS + idx * L3C + t], acc);
        s_p2[t] = clip01(acc) * W3[t * COUNT + idx];
    }
    __syncthreads();

    if (t == 0) {
        float s = 0.0f;
        #pragma unroll
        for (int m = 0; m < L3C; ++m) s += s_p2[m];
        out[b] = s + b3[idx] + s_l1f;
    }
}

extern "C" void kernel_launch(void* const* d_in, const int* in_sizes, int n_in,
                              void* d_out, int out_size, void* d_ws, size_t ws_size,
                              hipStream_t stream) {
    const float* us   = (const float*)d_in[0];
    const float* them = (const float*)d_in[1];
    const int*   wi   = (const int*)  d_in[2];
    const float* wv   = (const float*)d_in[3];
    const int*   bi   = (const int*)  d_in[4];
    const float* bv   = (const float*)d_in[5];
    const int*   lsi  = (const int*)  d_in[6];
    const float* W_ft = (const float*)d_in[7];
    const float* b_ft = (const float*)d_in[8];
    const float* W1   = (const float*)d_in[9];
    const float* b1   = (const float*)d_in[10];
    const float* W2   = (const float*)d_in[11];
    const float* b2   = (const float*)d_in[12];
    const float* W3   = (const float*)d_in[13];
    const float* b3   = (const float*)d_in[14];
    float*       out  = (float*)d_out;

    const int Bn = in_sizes[0]; // 4096 batch rows
    const size_t qTableBytes = (size_t)NF * L1;                  // 23.1 MB
    const size_t needed      = qTableBytes + (size_t)NF * sizeof(float);

    if (ws_size >= needed) {
        unsigned char* Wq  = (unsigned char*)d_ws;
        float*         scl = (float*)((char*)d_ws + qTableBytes);
        quant_w_ft<<<(NF + 3) / 4, 256, 0, stream>>>(W_ft, Wq, scl, NF);
        nnue_fused_q2<<<(Bn + 1) / 2, BDIM, 0, stream>>>(us, them, wi, wv, bi, bv, lsi,
                                                         Wq, scl, b_ft, W1, b1, W2, b2,
                                                         W3, b3, out, Bn);
    } else {
        nnue_fused_f<<<Bn, BDIM, 0, stream>>>(us, them, wi, wv, bi, bv, lsi,
                                              W_ft, b_ft, W1, b1, W2, b2, W3, b3, out);
    }
}

// Round 9
// 233.216 us; speedup vs baseline: 1.0229x; 1.0229x over previous
//
#include <hip/hip_runtime.h>

#define BDIM 256

constexpr int K      = 32;
constexpr int L1     = 1024;
constexpr int L2C    = 15;
constexpr int L3C    = 32;
constexpr int COUNT  = 9;
constexpr int NF     = 22528;
constexpr int W1COLS = COUNT * (L2C + 1); // 144
constexpr int W2COLS = COUNT * L3C;       // 288

__device__ __forceinline__ float clip01(float x) {
    return fminf(fmaxf(x, 0.0f), 1.0f);
}

// ---- fp32 -> uint8 (excess-128) per-row quantization of W_ft ----
// Lane owns 16 consecutive cols -> one uint4 (16 B) store per lane.
// Rebuilt every iteration (workspace re-poisoned; R1 proved memoization
// never survives). ~33 us measured-equivalent (R3 cvt analog).
__global__ __launch_bounds__(256) void quant_w_ft(const float* __restrict__ src,
                                                  unsigned char* __restrict__ dst,
                                                  float* __restrict__ scales,
                                                  int nrows) {
    const int wq   = threadIdx.x >> 6;          // wave in block
    const int lane = threadIdx.x & 63;
    const int row  = blockIdx.x * 4 + wq;
    if (row >= nrows) return;

    const float* s = src + (long)row * L1 + lane * 16;
    float4 v[4];
    v[0] = *(const float4*)(s);
    v[1] = *(const float4*)(s + 4);
    v[2] = *(const float4*)(s + 8);
    v[3] = *(const float4*)(s + 12);

    float m = 0.0f;
    #pragma unroll
    for (int i = 0; i < 4; ++i)
        m = fmaxf(m, fmaxf(fmaxf(fabsf(v[i].x), fabsf(v[i].y)),
                           fmaxf(fabsf(v[i].z), fabsf(v[i].w))));
    #pragma unroll
    for (int off = 32; off >= 1; off >>= 1)
        m = fmaxf(m, __shfl_xor(m, off));

    const float mm    = fmaxf(m, 1e-30f);
    const float scale = mm / 127.0f;
    const float inv   = 127.0f / mm;

    uint4 pk;
    unsigned* pw = (unsigned*)&pk;
    #pragma unroll
    for (int i = 0; i < 4; ++i) {
        int q0 = (int)rintf(v[i].x * inv) + 128;
        int q1 = (int)rintf(v[i].y * inv) + 128;
        int q2 = (int)rintf(v[i].z * inv) + 128;
        int q3 = (int)rintf(v[i].w * inv) + 128;
        q0 = max(0, min(255, q0)); q1 = max(0, min(255, q1));
        q2 = max(0, min(255, q2)); q3 = max(0, min(255, q3));
        pw[i] = (unsigned)q0 | ((unsigned)q1 << 8) |
                ((unsigned)q2 << 16) | ((unsigned)q3 << 24);
    }
    *(uint4*)(dst + (long)row * L1 + lane * 16) = pk;
    if (lane == 0) scales[row] = scale;
}

// ---- fused NNUE forward, uint8 table (exact R4 structure) ----
// R9: single change vs the verified 71.2 us build -- k-loop unroll 8 -> 16,
// doubling per-wave outstanding loads. This is the one untested mechanism
// after R5 (instr count), R6 (bank conflicts), R7 (unpack), R8 (2-row ILP)
// all failed to move the 71 us attractor.
__global__ __launch_bounds__(BDIM) void nnue_fused_q(
    const float* __restrict__ us,
    const float* __restrict__ them,
    const int*   __restrict__ wi,
    const float* __restrict__ wv,
    const int*   __restrict__ bi,
    const float* __restrict__ bvv,
    const int*   __restrict__ lsi,
    const unsigned char* __restrict__ Wq,
    const float* __restrict__ scl,
    const float* __restrict__ b_ft,
    const float* __restrict__ W1,
    const float* __restrict__ b1,
    const float* __restrict__ W2,
    const float* __restrict__ b2,
    const float* __restrict__ W3,
    const float* __restrict__ b3,
    float* __restrict__ out)
{
    const int b = blockIdx.x;
    const int t = threadIdx.x;

    __shared__ int   s_idx[2 * K];
    __shared__ float s_val[2 * K];   // val * scale[row]
    __shared__ float s_wp[L1];
    __shared__ float s_bp[L1];
    __shared__ float s_red[4 * 16];
    __shared__ float s_v[2 * L2C];
    __shared__ float s_p2[L3C];
    __shared__ float s_l1f;

    // ---- stage sparse indices/values (scale folded into value) ----
    if (t < K) {
        const int ii = wi[b * K + t];
        s_idx[t] = ii;
        s_val[t] = wv[b * K + t] * scl[ii];
    } else if (t < 2 * K) {
        const int ii = bi[b * K + (t - K)];
        s_idx[t] = ii;
        s_val[t] = bvv[b * K + (t - K)] * scl[ii];
    }
    __syncthreads();

    // ---- feature transform: 8 B per row access per lane ----
    const int   half = t >> 7;        // 0 = white, 1 = black
    const int   tc   = t & 127;
    const int   c8   = tc * 8;        // byte offset == col offset (1 B/col)
    const int*   idxs = s_idx + half * K;
    const float* vals = s_val + half * K;

    float acc[8];
    {
        const float4 bf0 = *(const float4*)(b_ft + c8);
        const float4 bf1 = *(const float4*)(b_ft + c8 + 4);
        acc[0] = bf0.x; acc[1] = bf0.y; acc[2] = bf0.z; acc[3] = bf0.w;
        acc[4] = bf1.x; acc[5] = bf1.y; acc[6] = bf1.z; acc[7] = bf1.w;
    }

    float sumvs = 0.0f;
    #pragma unroll 16
    for (int k = 0; k < K; ++k) {
        const float vs = vals[k];
        const uint2 q  = *(const uint2*)(Wq + ((long)idxs[k] << 10) + c8);
        sumvs += vs;
        acc[0] = fmaf(vs, (float)( q.x        & 0xffu), acc[0]);
        acc[1] = fmaf(vs, (float)((q.x >>  8) & 0xffu), acc[1]);
        acc[2] = fmaf(vs, (float)((q.x >> 16) & 0xffu), acc[2]);
        acc[3] = fmaf(vs, (float)( q.x >> 24        ), acc[3]);
        acc[4] = fmaf(vs, (float)( q.y        & 0xffu), acc[4]);
        acc[5] = fmaf(vs, (float)((q.y >>  8) & 0xffu), acc[5]);
        acc[6] = fmaf(vs, (float)((q.y >> 16) & 0xffu), acc[6]);
        acc[7] = fmaf(vs, (float)( q.y >> 24        ), acc[7]);
    }
    // remove the excess-128 bias in one fma per element
    #pragma unroll
    for (int j = 0; j < 8; ++j) acc[j] = fmaf(sumvs, -128.0f, acc[j]);

    {
        float* dst = (half == 0 ? s_wp : s_bp) + c8;
        #pragma unroll
        for (int j = 0; j < 8; ++j) dst[j] = acc[j];
    }
    __syncthreads();

    const float u   = us[b];
    const float th  = them[b];
    const int   idx = lsi[b];
    const float cc  = 127.0f / 128.0f;

    // ---- layer 1 ----
    float p[16];
    #pragma unroll
    for (int j = 0; j < 16; ++j) p[j] = 0.0f;

    const float* W1sel = W1 + idx * (L2C + 1);
    const int e0 = t * 4;
    #pragma unroll
    for (int q = 0; q < 4; ++q) {
        const int e = e0 + q;
        float l0p;
        if (e < 512) {
            const float a0 = clip01(u * s_wp[e]       + th * s_bp[e]);
            const float a1 = clip01(u * s_wp[e + 512] + th * s_bp[e + 512]);
            l0p = a0 * a1;
        } else {
            const int   c   = e - 512;
            const float b0  = clip01(u * s_bp[c] + th * s_wp[c]);
            const float b1v = clip01(u * s_bp[e] + th * s_wp[e]);
            l0p = b0 * b1v;
        }
        l0p *= cc;
        const float* wrow = W1sel + e * W1COLS;
        #pragma unroll
        for (int j = 0; j < 16; ++j) p[j] = fmaf(l0p, wrow[j], p[j]);
    }

    const int lane = t & 63;
    const int wid  = t >> 6;
    #pragma unroll
    for (int j = 0; j < 16; ++j) {
        float v = p[j];
        v += __shfl_down(v, 32);
        v += __shfl_down(v, 16);
        v += __shfl_down(v, 8);
        v += __shfl_down(v, 4);
        v += __shfl_down(v, 2);
        v += __shfl_down(v, 1);
        if (lane == 0) s_red[wid * 16 + j] = v;
    }
    __syncthreads();

    if (t < 16) {
        float x1 = s_red[t] + s_red[16 + t] + s_red[32 + t] + s_red[48 + t]
                 + b1[idx * (L2C + 1) + t];
        if (t == 15) {
            s_l1f = x1;
        } else {
            float cx = clip01(x1);
            s_v[t]       = cx * cx * cc;
            s_v[L2C + t] = cx * cc;
        }
    }
    __syncthreads();

    if (t < L3C) {
        float acc2 = b2[idx * L3C + t];
        #pragma unroll
        for (int r = 0; r < 2 * L2C; ++r)
            acc2 = fmaf(s_v[r], W2[r * W2COLS + idx * L3C + t], acc2);
        s_p2[t] = clip01(acc2) * W3[t * COUNT + idx];
    }
    __syncthreads();

    if (t == 0) {
        float s = 0.0f;
        #pragma unroll
        for (int m = 0; m < L3C; ++m) s += s_p2[m];
        out[b] = s + b3[idx] + s_l1f;
    }
}

// ---- fp32 single-kernel fallback (ws too small) — verified 186 us ----
__global__ __launch_bounds__(BDIM) void nnue_fused_f(
    const float* __restrict__ us,
    const float* __restrict__ them,
    const int*   __restrict__ wi,
    const float* __restrict__ wv,
    const int*   __restrict__ bi,
    const float* __restrict__ bvv,
    const int*   __restrict__ lsi,
    const float* __restrict__ W_ft,
    const float* __restrict__ b_ft,
    const float* __restrict__ W1,
    const float* __restrict__ b1,
    const float* __restrict__ W2,
    const float* __restrict__ b2,
    const float* __restrict__ W3,
    const float* __restrict__ b3,
    float* __restrict__ out)
{
    const int b = blockIdx.x;
    const int t = threadIdx.x;

    __shared__ int   s_idx[2 * K];
    __shared__ float s_val[2 * K];
    __shared__ float s_l0[2 * L1];
    __shared__ float s_red[4 * 16];
    __shared__ float s_v[2 * L2C];
    __shared__ float s_p2[L3C];
    __shared__ float s_l1f;

    if (t < K)          { s_idx[t] = wi[b * K + t];        s_val[t] = wv[b * K + t]; }
    else if (t < 2 * K) { s_idx[t] = bi[b * K + (t - K)];  s_val[t] = bvv[b * K + (t - K)]; }
    __syncthreads();

    const int c4 = t * 4;
    float4 accW = *(const float4*)(b_ft + c4);
    float4 accB = accW;

    #pragma unroll 8
    for (int k = 0; k < K; ++k) {
        const float  vwk = s_val[k];
        const float  vbk = s_val[K + k];
        const float4 rw  = *(const float4*)(W_ft + ((long)s_idx[k]     << 10) + c4);
        const float4 rb  = *(const float4*)(W_ft + ((long)s_idx[K + k] << 10) + c4);
        accW.x = fmaf(vwk, rw.x, accW.x);
        accW.y = fmaf(vwk, rw.y, accW.y);
        accW.z = fmaf(vwk, rw.z, accW.z);
        accW.w = fmaf(vwk, rw.w, accW.w);
        accB.x = fmaf(vbk, rb.x, accB.x);
        accB.y = fmaf(vbk, rb.y, accB.y);
        accB.z = fmaf(vbk, rb.z, accB.z);
        accB.w = fmaf(vbk, rb.w, accB.w);
    }

    const float u  = us[b];
    const float th = them[b];
    float4 A, Bv;
    A.x  = clip01(u * accW.x + th * accB.x);
    A.y  = clip01(u * accW.y + th * accB.y);
    A.z  = clip01(u * accW.z + th * accB.z);
    A.w  = clip01(u * accW.w + th * accB.w);
    Bv.x = clip01(u * accB.x + th * accW.x);
    Bv.y = clip01(u * accB.y + th * accW.y);
    Bv.z = clip01(u * accB.z + th * accW.z);
    Bv.w = clip01(u * accB.w + th * accW.w);
    *(float4*)(s_l0 + c4)      = A;
    *(float4*)(s_l0 + L1 + c4) = Bv;
    __syncthreads();

    const int   idx = lsi[b];
    const float cc  = 127.0f / 128.0f;

    float p[16];
    #pragma unroll
    for (int j = 0; j < 16; ++j) p[j] = 0.0f;

    const float* W1sel = W1 + idx * (L2C + 1);
    #pragma unroll
    for (int q = 0; q < 4; ++q) {
        const int e = c4 + q;
        float l0p;
        if (e < 512) l0p = s_l0[e] * s_l0[e + 512];
        else         l0p = s_l0[e + 512] * s_l0[e + 1024];
        l0p *= cc;
        const float* wrow = W1sel + e * W1COLS;
        #pragma unroll
        for (int j = 0; j < 16; ++j) p[j] = fmaf(l0p, wrow[j], p[j]);
    }

    const int lane = t & 63;
    const int wid  = t >> 6;
    #pragma unroll
    for (int j = 0; j < 16; ++j) {
        float v = p[j];
        v += __shfl_down(v, 32);
        v += __shfl_down(v, 16);
        v += __shfl_down(v, 8);
        v += __shfl_down(v, 4);
        v += __shfl_down(v, 2);
        v += __shfl_down(v, 1);
        if (lane == 0) s_red[wid * 16 + j] = v;
    }
    __syncthreads();

    if (t < 16) {
        float x1 = s_red[t] + s_red[16 + t] + s_red[32 + t] + s_red[48 + t]
                 + b1[idx * (L2C + 1) + t];
        if (t == 15) {
            s_l1f = x1;
        } else {
            float cx = clip01(x1);
            s_v[t]       = cx * cx * cc;
            s_v[L2C + t] = cx * cc;
        }
    }
    __syncthreads();

    if (t < L3C) {
        float acc = b2[idx * L3C + t];
        #pragma unroll
        for (int r = 0; r < 2 * L2C; ++r)
            acc = fmaf(s_v[r], W2[r * W2COLS + idx * L3C + t], acc);
        s_p2[t] = clip01(acc) * W3[t * COUNT + idx];
    }
    __syncthreads();

    if (t == 0) {
        float s = 0.0f;
        #pragma unroll
        for (int m = 0; m < L3C; ++m) s += s_p2[m];
        out[b] = s + b3[idx] + s_l1f;
    }
}

extern "C" void kernel_launch(void* const* d_in, const int* in_sizes, int n_in,
                              void* d_out, int out_size, void* d_ws, size_t ws_size,
                              hipStream_t stream) {
    const float* us   = (const float*)d_in[0];
    const float* them = (const float*)d_in[1];
    const int*   wi   = (const int*)  d_in[2];
    const float* wv   = (const float*)d_in[3];
    const int*   bi   = (const int*)  d_in[4];
    const float* bv   = (const float*)d_in[5];
    const int*   lsi  = (const int*)  d_in[6];
    const float* W_ft = (const float*)d_in[7];
    const float* b_ft = (const float*)d_in[8];
    const float* W1   = (const float*)d_in[9];
    const float* b1   = (const float*)d_in[10];
    const float* W2   = (const float*)d_in[11];
    const float* b2   = (const float*)d_in[12];
    const float* W3   = (const float*)d_in[13];
    const float* b3   = (const float*)d_in[14];
    float*       out  = (float*)d_out;

    const int Bn = in_sizes[0]; // 4096 batch rows
    const size_t qTableBytes = (size_t)NF * L1;                  // 23.1 MB
    const size_t needed      = qTableBytes + (size_t)NF * sizeof(float);

    if (ws_size >= needed) {
        unsigned char* Wq  = (unsigned char*)d_ws;
        float*         scl = (float*)((char*)d_ws + qTableBytes);
        quant_w_ft<<<(NF + 3) / 4, 256, 0, stream>>>(W_ft, Wq, scl, NF);
        nnue_fused_q<<<Bn, BDIM, 0, stream>>>(us, them, wi, wv, bi, bv, lsi,
                                              Wq, scl, b_ft, W1, b1, W2, b2, W3, b3, out);
    } else {
        nnue_fused_f<<<Bn, BDIM, 0, stream>>>(us, them, wi, wv, bi, bv, lsi,
                                              W_ft, b_ft, W1, b1, W2, b2, W3, b3, out);
    }
}